// Round 2
// baseline (86.243 us; speedup 1.0000x reference)
//
#include <hip/hip_runtime.h>
#include <math.h>

#define MAXR 100.0f
#define LOG2E 1.4426950408889634f
// Fixed shapes: B=4, C=64, H=64, W=64; conv (2,64,3,3) OIHW, SAME.

__device__ __forceinline__ float exp2_fast(float x) { return __builtin_amdgcn_exp2f(x); }
__device__ __forceinline__ float rcp_fast(float x)  { return __builtin_amdgcn_rcpf(x); }
__device__ __forceinline__ float bcast_lane(float v, int i) {
    return __int_as_float(__builtin_amdgcn_readlane(__float_as_int(v), i));
}

__device__ __forceinline__ float tanh_fast(float s) {
    // tanh(s) = sign(s) * (1 - 2/(e^{2|s|}+1)); E=inf -> t=1 exactly
    float E = exp2_fast(2.0f * LOG2E * fabsf(s));
    float t = fmaf(-2.0f, rcp_fast(E + 1.0f), 1.0f);
    return copysignf(t, s);
}

// ---- DPP wave64 reductions: VALU-only (no LDS pipe, no lgkmcnt chains) ----
// sum: invalid lanes contribute 0 (bound_ctrl=1)
template<int CTRL>
__device__ __forceinline__ float dpp0(float v) {
    return __int_as_float(__builtin_amdgcn_update_dpp(0, __float_as_int(v), CTRL, 0xf, 0xf, true));
}
// keep-old variant for max (invalid lanes yield own value)
template<int CTRL>
__device__ __forceinline__ float dppk(float v) {
    return __int_as_float(__builtin_amdgcn_update_dpp(__float_as_int(v), __float_as_int(v), CTRL, 0xf, 0xf, false));
}
__device__ __forceinline__ float wave_sum(float v) {
    v += dpp0<0x111>(v);   // row_shr:1
    v += dpp0<0x112>(v);   // row_shr:2
    v += dpp0<0x114>(v);   // row_shr:4
    v += dpp0<0x118>(v);   // row_shr:8  -> lane15 of each row = row sum
    v += dpp0<0x142>(v);   // row_bcast15
    v += dpp0<0x143>(v);   // row_bcast31 -> lane63 = total
    return bcast_lane(v, 63);
}
__device__ __forceinline__ float wave_max(float v) {
    v = fmaxf(v, dppk<0x111>(v));
    v = fmaxf(v, dppk<0x112>(v));
    v = fmaxf(v, dppk<0x114>(v));
    v = fmaxf(v, dppk<0x118>(v));
    v = fmaxf(v, dppk<0x142>(v));
    v = fmaxf(v, dppk<0x143>(v));
    return bcast_lane(v, 63);
}

// 1024 blocks x 256 threads. Block = 16 consecutive-w pixels (same b,h);
// wave = 4 pixels (ILP-4 per lane); lane = channel.
// LDS: 64c x 3r x 18w window, row stride 19, c stride 57 (gcd(57,32)=1).
__global__ __launch_bounds__(256, 4) void dsf_fused(const float* __restrict__ x,
                                                    const float* __restrict__ wg,
                                                    const float* __restrict__ bias,
                                                    float* __restrict__ out) {
    __shared__ float xs[64 * 57];       // 14.6 KB

    const int tid  = threadIdx.x;
    const int lane = tid & 63;
    const int wave = tid >> 6;

    const int p0 = blockIdx.x * 16;     // b*4096 + h*64 + w0, w0 multiple of 16
    const int b  = p0 >> 12;
    const int h  = (p0 >> 6) & 63;
    const int w0 = p0 & 63;

    // per-lane conv weights (channel = lane): 18 dwords, L1/L2-hot
    float wr0[9], wr1[9];
    #pragma unroll
    for (int k = 0; k < 9; ++k) {
        wr0[k] = wg[lane * 9 + k];
        wr1[k] = wg[576 + lane * 9 + k];
    }
    const float b0 = bias[0], b1 = bias[1];

    // stage x[b, :, h-1:h+2, w0-1:w0+17) zero-padded into xs
    const float* xbase = x + b * 262144;
    for (int e = tid; e < 3456; e += 256) {
        int c   = e / 54;
        int rem = e - c * 54;
        int r   = rem / 18;
        int wt  = rem - r * 18;
        int hh  = h + r - 1;
        int ww  = w0 - 1 + wt;
        float v = 0.f;
        if (hh >= 0 && hh < 64 && (unsigned)ww < 64u)
            v = xbase[c * 4096 + hh * 64 + ww];
        xs[c * 57 + r * 19 + wt] = v;
    }
    __syncthreads();

    // ---- per-lane window for this wave's 4 pixels: cols wave*4 .. wave*4+5 ----
    const float* xc = xs + lane * 57;
    float win[3][6];
    #pragma unroll
    for (int r = 0; r < 3; ++r)
        #pragma unroll
        for (int t = 0; t < 6; ++t)
            win[r][t] = xc[r * 19 + wave * 4 + t];

    // ---- conv + alpha/beta per pixel (DPP sum over channels) ----
    float be[4], aa[4], c2[4], xj[4];
    #pragma unroll
    for (int p = 0; p < 4; ++p) {
        float a0 = 0.f, a1 = 0.f;
        #pragma unroll
        for (int r = 0; r < 3; ++r) {
            #pragma unroll
            for (int t = 0; t < 3; ++t) {
                float xv = win[r][p + t];
                a0 = fmaf(xv, wr0[r * 3 + t], a0);
                a1 = fmaf(xv, wr1[r * 3 + t], a1);
            }
        }
        a0 = wave_sum(a0);
        a1 = wave_sum(a1);
        float al = MAXR * tanh_fast(a0 + b0);      // alpha (wave-uniform)
        be[p]    = MAXR * tanh_fast(a1 + b1);      // beta
        aa[p]    = fabsf(al);
        c2[p]    = 2.0f * LOG2E * aa[p];           // t = 1 - 2/(2^(c2*|d|)+1)
        xj[p]    = win[1][p + 1];                  // x[b, lane, h, w0+wave*4+p]
    }

    // ---- pairwise: A_j = sum_i |be*x_i - x_j| * tanh(aa*|...|), ILP-4 ----
    float A[4] = {0.f, 0.f, 0.f, 0.f};
    #pragma unroll 4
    for (int i = 0; i < 64; ++i) {
        #pragma unroll
        for (int p = 0; p < 4; ++p) {
            float s = bcast_lane(xj[p], i);
            float d = fmaf(be[p], s, -xj[p]);
            float E = exp2_fast(c2[p] * fabsf(d));
            float r = rcp_fast(E + 1.0f);
            float u = fmaf(-2.0f, r, 1.0f);
            A[p] = fmaf(fabsf(d), u, A[p]);
        }
    }

    // ---- softmax over channels + weighted sum, per pixel ----
    #pragma unroll
    for (int p = 0; p < 4; ++p) {
        // logits: g_j = max(-A*|alpha|/64, -100)  (sign(alpha) cancels exactly)
        float gl = fmaxf(-A[p] * aa[p] * (1.0f / 64.0f), -MAXR);
        float gm = wave_max(gl);
        float ew = exp2_fast((gl - gm) * LOG2E);
        float den = wave_sum(ew);
        float num = wave_sum(xj[p] * ew);
        if (lane == 0) out[p0 + wave * 4 + p] = num * rcp_fast(den);  // den >= 1
    }
}

extern "C" void kernel_launch(void* const* d_in, const int* in_sizes, int n_in,
                              void* d_out, int out_size, void* d_ws, size_t ws_size,
                              hipStream_t stream) {
    const float* x      = (const float*)d_in[0];   // (4,64,64,64)
    const float* conv_w = (const float*)d_in[1];   // (2,64,3,3)
    const float* conv_b = (const float*)d_in[2];   // (2,)
    float* out = (float*)d_out;                    // (4,1,64,64)
    (void)d_ws; (void)ws_size;

    dsf_fused<<<1024, 256, 0, stream>>>(x, conv_w, conv_b, out);
}

// Round 3
// 77.780 us; speedup vs baseline: 1.1088x; 1.1088x over previous
//
#include <hip/hip_runtime.h>
#include <math.h>

#define MAXR 100.0f
#define LOG2E 1.4426950408889634f
// Fixed shapes: B=4, C=64, H=64, W=64; conv (2,64,3,3) OIHW, SAME.

__device__ __forceinline__ float exp2_fast(float x) { return __builtin_amdgcn_exp2f(x); }
__device__ __forceinline__ float rcp_fast(float x)  { return __builtin_amdgcn_rcpf(x); }
__device__ __forceinline__ float bcast_lane(float v, int i) {
    return __int_as_float(__builtin_amdgcn_readlane(__float_as_int(v), i));
}

__device__ __forceinline__ float tanh_fast(float s) {
    // tanh(s) = sign(s) * (1 - 2/(e^{2|s|}+1)); E=inf -> t=1 exactly
    float E = exp2_fast(2.0f * LOG2E * fabsf(s));
    float t = fmaf(-2.0f, rcp_fast(E + 1.0f), 1.0f);
    return copysignf(t, s);
}

// ---- DPP wave64 reductions: VALU-only (verified on HW in round 2) ----
template<int CTRL>
__device__ __forceinline__ float dpp0(float v) {
    return __int_as_float(__builtin_amdgcn_update_dpp(0, __float_as_int(v), CTRL, 0xf, 0xf, true));
}
template<int CTRL>
__device__ __forceinline__ float dppk(float v) {
    return __int_as_float(__builtin_amdgcn_update_dpp(__float_as_int(v), __float_as_int(v), CTRL, 0xf, 0xf, false));
}
__device__ __forceinline__ float wave_sum(float v) {
    v += dpp0<0x111>(v);   // row_shr:1
    v += dpp0<0x112>(v);   // row_shr:2
    v += dpp0<0x114>(v);   // row_shr:4
    v += dpp0<0x118>(v);   // row_shr:8
    v += dpp0<0x142>(v);   // row_bcast15
    v += dpp0<0x143>(v);   // row_bcast31 -> lane63 = total
    return bcast_lane(v, 63);
}
__device__ __forceinline__ float wave_max(float v) {
    v = fmaxf(v, dppk<0x111>(v));
    v = fmaxf(v, dppk<0x112>(v));
    v = fmaxf(v, dppk<0x114>(v));
    v = fmaxf(v, dppk<0x118>(v));
    v = fmaxf(v, dppk<0x142>(v));
    v = fmaxf(v, dppk<0x143>(v));
    return bcast_lane(v, 63);
}

// 4096 blocks x 256 threads. Block = 4 consecutive-w pixels (same b,h);
// ONE pixel per wave; lane = channel. Saturation-skip pairwise loop:
// u = 1 - 2/(2^m+1) rounds to exactly 1.0f for m >= 28, so groups of 4
// i-values where ALL lanes saturate take a TRANS-free path (bitwise-equal).
__global__ __launch_bounds__(256) void dsf_fused(const float* __restrict__ x,
                                                 const float* __restrict__ wg,
                                                 const float* __restrict__ bias,
                                                 float* __restrict__ out) {
    __shared__ float xs[64 * 19];       // [c][r*6+wt], stride 19 (gcd(19,32)=1)

    const int tid  = threadIdx.x;
    const int lane = tid & 63;
    const int wave = tid >> 6;

    const int p0 = blockIdx.x * 4;      // b*4096 + h*64 + w0, w0 multiple of 4
    const int b  = p0 >> 12;
    const int h  = (p0 >> 6) & 63;
    const int w0 = p0 & 63;

    // per-lane conv weights (channel = lane): 18 dwords, L2-hot
    float wr0[9], wr1[9];
    #pragma unroll
    for (int k = 0; k < 9; ++k) {
        wr0[k] = wg[lane * 9 + k];
        wr1[k] = wg[576 + lane * 9 + k];
    }
    const float b0 = bias[0], b1 = bias[1];

    // stage x[b, :, h-1:h+2, w0-1:w0+4] zero-padded into xs
    const float* xbase = x + b * 262144;
    for (int e = tid; e < 1152; e += 256) {
        int c   = e / 18;
        int rem = e - c * 18;
        int r   = rem / 6;
        int wt  = rem - r * 6;
        int hh  = h + r - 1;
        int ww  = w0 - 1 + wt;
        float v = 0.f;
        if (hh >= 0 && hh < 64 && (unsigned)ww < 64u)
            v = xbase[c * 4096 + hh * 64 + ww];
        xs[c * 19 + rem] = v;
    }
    __syncthreads();

    // ---- conv for this wave's pixel: lane sums its channel's 9 taps ----
    const float* xc = xs + lane * 19;
    float a0 = 0.f, a1 = 0.f;
    #pragma unroll
    for (int r = 0; r < 3; ++r) {
        #pragma unroll
        for (int t = 0; t < 3; ++t) {
            float xv = xc[r * 6 + wave + t];
            a0 = fmaf(xv, wr0[r * 3 + t], a0);
            a1 = fmaf(xv, wr1[r * 3 + t], a1);
        }
    }
    a0 = wave_sum(a0);
    a1 = wave_sum(a1);
    const float al = MAXR * tanh_fast(a0 + b0);    // alpha (wave-uniform)
    const float be = MAXR * tanh_fast(a1 + b1);    // beta
    const float aa = fabsf(al);
    const float c2 = 2.0f * LOG2E * aa;            // u = 1 - 2/(2^(c2*|d|)+1)

    const float xj = xc[6 + wave + 1];             // x[b, lane, h, w0+wave]

    // ---- pairwise: A_j = sum_i |d| * u(|d|), saturation-skip groups of 4 ----
    float A0 = 0.f, A1 = 0.f, A2 = 0.f, A3 = 0.f;
    #pragma unroll
    for (int i = 0; i < 64; i += 4) {
        float s0 = bcast_lane(xj, i + 0);
        float s1 = bcast_lane(xj, i + 1);
        float s2 = bcast_lane(xj, i + 2);
        float s3 = bcast_lane(xj, i + 3);
        float d0 = fabsf(fmaf(be, s0, -xj));
        float d1 = fabsf(fmaf(be, s1, -xj));
        float d2 = fabsf(fmaf(be, s2, -xj));
        float d3 = fabsf(fmaf(be, s3, -xj));
        float m0 = c2 * d0;
        float m1 = c2 * d1;
        float m2 = c2 * d2;
        float m3 = c2 * d3;
        float mn = fminf(fminf(m0, m1), fminf(m2, m3));
        if (__all(mn >= 28.0f)) {
            // u == 1.0f exactly for every lane: A += |d| (bitwise-equal)
            A0 += d0; A1 += d1; A2 += d2; A3 += d3;
        } else {
            float E0 = exp2_fast(m0);
            float E1 = exp2_fast(m1);
            float E2 = exp2_fast(m2);
            float E3 = exp2_fast(m3);
            float r0 = rcp_fast(E0 + 1.f);
            float r1 = rcp_fast(E1 + 1.f);
            float r2 = rcp_fast(E2 + 1.f);
            float r3 = rcp_fast(E3 + 1.f);
            A0 = fmaf(d0, fmaf(-2.f, r0, 1.f), A0);
            A1 = fmaf(d1, fmaf(-2.f, r1, 1.f), A1);
            A2 = fmaf(d2, fmaf(-2.f, r2, 1.f), A2);
            A3 = fmaf(d3, fmaf(-2.f, r3, 1.f), A3);
        }
    }
    float A = (A0 + A1) + (A2 + A3);

    // logits: g_j = max(-A*|alpha|/64, -100)  (sign(alpha) cancels exactly)
    float gl = fmaxf(-A * aa * (1.0f / 64.0f), -MAXR);

    float gm = wave_max(gl);
    float ew  = exp2_fast((gl - gm) * LOG2E);
    float den = wave_sum(ew);
    float num = wave_sum(xj * ew);
    if (lane == 0) out[p0 + wave] = num * rcp_fast(den);   // den >= 1
}

extern "C" void kernel_launch(void* const* d_in, const int* in_sizes, int n_in,
                              void* d_out, int out_size, void* d_ws, size_t ws_size,
                              hipStream_t stream) {
    const float* x      = (const float*)d_in[0];   // (4,64,64,64)
    const float* conv_w = (const float*)d_in[1];   // (2,64,3,3)
    const float* conv_b = (const float*)d_in[2];   // (2,)
    float* out = (float*)d_out;                    // (4,1,64,64)
    (void)d_ws; (void)ws_size;

    dsf_fused<<<4096, 256, 0, stream>>>(x, conv_w, conv_b, out);
}

// Round 5
// 73.507 us; speedup vs baseline: 1.1733x; 1.0581x over previous
//
#include <hip/hip_runtime.h>
#include <math.h>

#define MAXR 100.0f
#define LOG2E 1.4426950408889634f
// Fixed shapes: B=4, C=64, H=64, W=64; conv (2,64,3,3) OIHW, SAME.

__device__ __forceinline__ float exp2_fast(float x) { return __builtin_amdgcn_exp2f(x); }
__device__ __forceinline__ float rcp_fast(float x)  { return __builtin_amdgcn_rcpf(x); }
__device__ __forceinline__ float bcast_lane(float v, int i) {   // i may be runtime (SGPR)
    return __int_as_float(__builtin_amdgcn_readlane(__float_as_int(v), i));
}

__device__ __forceinline__ float tanh_fast(float s) {
    // tanh(s) = sign(s) * (1 - 2/(e^{2|s|}+1)); E=inf -> t=1 exactly
    float E = exp2_fast(2.0f * LOG2E * fabsf(s));
    float t = fmaf(-2.0f, rcp_fast(E + 1.0f), 1.0f);
    return copysignf(t, s);
}

// ---- DPP wave64 reductions: VALU-only (HW-verified rounds 2-3) ----
template<int CTRL>
__device__ __forceinline__ float dpp0(float v) {
    return __int_as_float(__builtin_amdgcn_update_dpp(0, __float_as_int(v), CTRL, 0xf, 0xf, true));
}
template<int CTRL>
__device__ __forceinline__ float dppk(float v) {
    return __int_as_float(__builtin_amdgcn_update_dpp(__float_as_int(v), __float_as_int(v), CTRL, 0xf, 0xf, false));
}
__device__ __forceinline__ float wave_sum(float v) {
    v += dpp0<0x111>(v);   // row_shr:1
    v += dpp0<0x112>(v);   // row_shr:2
    v += dpp0<0x114>(v);   // row_shr:4
    v += dpp0<0x118>(v);   // row_shr:8
    v += dpp0<0x142>(v);   // row_bcast15
    v += dpp0<0x143>(v);   // row_bcast31 -> lane63 = total
    return bcast_lane(v, 63);
}
__device__ __forceinline__ float wave_max(float v) {
    v = fmaxf(v, dppk<0x111>(v));
    v = fmaxf(v, dppk<0x112>(v));
    v = fmaxf(v, dppk<0x114>(v));
    v = fmaxf(v, dppk<0x118>(v));
    v = fmaxf(v, dppk<0x142>(v));
    v = fmaxf(v, dppk<0x143>(v));
    return bcast_lane(v, 63);
}
__device__ __forceinline__ float wave_min(float v) {
    v = fminf(v, dppk<0x111>(v));
    v = fminf(v, dppk<0x112>(v));
    v = fminf(v, dppk<0x114>(v));
    v = fminf(v, dppk<0x118>(v));
    v = fminf(v, dppk<0x142>(v));
    v = fminf(v, dppk<0x143>(v));
    return bcast_lane(v, 63);
}

// 4096 blocks x 256 threads. Block = 4 consecutive-w pixels (same b,h);
// ONE pixel per wave; lane = channel.
// Pairwise stage collapsed via wave-uniform saturation classification:
//   i "easy-pos"  if be*x_i >= max_j(x_j) + 29/c2  -> u==1.0f exactly, d>0 all lanes
//   i "easy-neg"  if be*x_i <= min_j(x_j) - 29/c2  -> u==1.0f exactly, d<0 all lanes
//   A_j = (SP - SN) + (CN - CP)*x_j + sum_{hard i} full-eval
// Easy i's cost O(1) per wave (2 masked DPP sums + popcounts) instead of O(64).
__global__ __launch_bounds__(256) void dsf_fused(const float* __restrict__ x,
                                                 const float* __restrict__ wg,
                                                 const float* __restrict__ bias,
                                                 float* __restrict__ out) {
    __shared__ float xs[64 * 19];       // [c][r*6+wt], stride 19 (gcd(19,32)=1)

    const int tid  = threadIdx.x;
    const int lane = tid & 63;
    const int wave = tid >> 6;

    const int p0 = blockIdx.x * 4;      // b*4096 + h*64 + w0, w0 multiple of 4
    const int b  = p0 >> 12;
    const int h  = (p0 >> 6) & 63;
    const int w0 = p0 & 63;

    // per-lane conv weights (channel = lane): 18 dwords, L2-hot
    float wr0[9], wr1[9];
    #pragma unroll
    for (int k = 0; k < 9; ++k) {
        wr0[k] = wg[lane * 9 + k];
        wr1[k] = wg[576 + lane * 9 + k];
    }
    const float b0 = bias[0], b1 = bias[1];

    // stage x[b, :, h-1:h+2, w0-1:w0+4] zero-padded into xs
    const float* xbase = x + b * 262144;
    for (int e = tid; e < 1152; e += 256) {
        int c   = e / 18;
        int rem = e - c * 18;
        int r   = rem / 6;
        int wt  = rem - r * 6;
        int hh  = h + r - 1;
        int ww  = w0 - 1 + wt;
        float v = 0.f;
        if (hh >= 0 && hh < 64 && (unsigned)ww < 64u)
            v = xbase[c * 4096 + hh * 64 + ww];
        xs[c * 19 + rem] = v;
    }
    __syncthreads();

    // ---- conv for this wave's pixel: lane sums its channel's 9 taps ----
    const float* xc = xs + lane * 19;
    float a0 = 0.f, a1 = 0.f;
    #pragma unroll
    for (int r = 0; r < 3; ++r) {
        #pragma unroll
        for (int t = 0; t < 3; ++t) {
            float xv = xc[r * 6 + wave + t];
            a0 = fmaf(xv, wr0[r * 3 + t], a0);
            a1 = fmaf(xv, wr1[r * 3 + t], a1);
        }
    }
    a0 = wave_sum(a0);
    a1 = wave_sum(a1);
    const float al = MAXR * tanh_fast(a0 + b0);    // alpha (wave-uniform)
    const float be = MAXR * tanh_fast(a1 + b1);    // beta
    const float aa = fabsf(al);
    const float c2 = 2.0f * LOG2E * aa;            // u = 1 - 2/(2^(c2*|d|)+1)

    const float xj = xc[6 + wave + 1];             // x[b, lane, h, w0+wave]

    // ---- pairwise stage via saturation classification ----
    const float M  = wave_max(xj);
    const float mN = wave_min(xj);
    // thr: margin 29 (>28 needed for exact u==1.0f) absorbs mul/rcp rounding.
    const float thr = 29.0f * rcp_fast(c2);        // inf if c2==0 -> all hard
    const float bx  = be * xj;                     // this lane's value as "i"

    const bool isp = bx >= M + thr;
    const bool isn = bx <= mN - thr;
    unsigned long long pm = __ballot(isp);
    unsigned long long nm = __ballot(isn);
    unsigned long long hm = ~(pm | nm);            // hard i's (wave-uniform)

    float SP = wave_sum(isp ? bx : 0.0f);
    float SN = wave_sum(isn ? bx : 0.0f);
    int   CP = __popcll(pm);
    int   CN = __popcll(nm);

    float A = (SP - SN) + (float)(CN - CP) * xj;

    while (hm) {                                   // wave-uniform loop, ~2-4 trips
        int i = __ffsll((long long)hm) - 1;
        hm &= hm - 1;
        float s = bcast_lane(xj, i);
        float d = fabsf(fmaf(be, s, -xj));
        float m = c2 * d;
        float E = exp2_fast(m);
        float r = rcp_fast(E + 1.0f);
        A = fmaf(d, fmaf(-2.0f, r, 1.0f), A);
    }

    // logits: g_j = max(-A*|alpha|/64, -100)  (sign(alpha) cancels exactly)
    float gl = fmaxf(-A * aa * (1.0f / 64.0f), -MAXR);

    float gm = wave_max(gl);
    float ew  = exp2_fast((gl - gm) * LOG2E);
    float den = wave_sum(ew);
    float num = wave_sum(xj * ew);
    if (lane == 0) out[p0 + wave] = num * rcp_fast(den);   // den >= 1
}

extern "C" void kernel_launch(void* const* d_in, const int* in_sizes, int n_in,
                              void* d_out, int out_size, void* d_ws, size_t ws_size,
                              hipStream_t stream) {
    const float* x      = (const float*)d_in[0];   // (4,64,64,64)
    const float* conv_w = (const float*)d_in[1];   // (2,64,3,3)
    const float* conv_b = (const float*)d_in[2];   // (2,)
    float* out = (float*)d_out;                    // (4,1,64,64)
    (void)d_ws; (void)ws_size;

    dsf_fused<<<4096, 256, 0, stream>>>(x, conv_w, conv_b, out);
}